// Round 1
// baseline (435.740 us; speedup 1.0000x reference)
//
#include <hip/hip_runtime.h>
#include <hip/hip_bf16.h>
#include <math.h>

using bf16x8 = __attribute__((ext_vector_type(8))) __bf16;
using f32x4  = __attribute__((ext_vector_type(4))) float;
typedef unsigned short ushort_t;

#define BS    8192
#define CDIM  512
#define MROWS 32768
#define NC    8                 // n-chunks (grid.x)
#define CHUNK (MROWS / NC)      // 4096
#define TN    32                // B-tile rows per iteration
#define TQ    128               // queries per block
#define KTOP  5

// ---------- key packing: monotonic fp32 order bits [31:15] | index [14:0] ----
__device__ __forceinline__ unsigned enc_key(float s, int n) {
    unsigned u = __float_as_uint(s);
    u ^= (unsigned)((int)u >> 31) | 0x80000000u;   // monotonic map
    return (u & 0xFFFF8000u) | (unsigned)n;
}
__device__ __forceinline__ float dec_score(unsigned k) {
    unsigned u = k & 0xFFFF8000u;
    u = (u & 0x80000000u) ? (u ^ 0x80000000u) : ~u;
    return __uint_as_float(u);
}

// sorted-descending top-5 list of packed keys, branchless bubble insert
__device__ __forceinline__ void ins_nb(unsigned (&ks)[KTOP], unsigned k) {
    unsigned t = k;
#pragma unroll
    for (int j = 0; j < KTOP; ++j) {
        unsigned hi = t > ks[j] ? t : ks[j];
        unsigned lo = t > ks[j] ? ks[j] : t;
        ks[j] = hi; t = lo;
    }
}
__device__ __forceinline__ void ins_guard(unsigned (&ks)[KTOP], unsigned k) {
    if (k > ks[KTOP - 1]) ins_nb(ks, k);
}

template <int BASE>
__device__ __forceinline__ void upd4(const f32x4 a, unsigned (&keys)[8][KTOP], int n) {
    ins_guard(keys[BASE + 0], enc_key(a[0], n));
    ins_guard(keys[BASE + 1], enc_key(a[1], n));
    ins_guard(keys[BASE + 2], enc_key(a[2], n));
    ins_guard(keys[BASE + 3], enc_key(a[3], n));
}

// ---------- kernel 1/2: row L2-normalize fp32 -> bf16 -----------------------
__global__ void nrm_cast(const float* __restrict__ in, ushort_t* __restrict__ out, int rows) {
    int wave = threadIdx.x >> 6, lane = threadIdx.x & 63;
    int row = blockIdx.x * 4 + wave;
    if (row >= rows) return;
    const float* rp = in + (size_t)row * CDIM + lane * 8;
    float4 v0 = *(const float4*)rp;
    float4 v1 = *(const float4*)(rp + 4);
    float ss = v0.x * v0.x + v0.y * v0.y + v0.z * v0.z + v0.w * v0.w
             + v1.x * v1.x + v1.y * v1.y + v1.z * v1.z + v1.w * v1.w;
#pragma unroll
    for (int d = 1; d < 64; d <<= 1) ss += __shfl_xor(ss, d);
    float sc = 1.0f / fmaxf(sqrtf(ss), 1e-12f);
    bf16x8 o;
    o[0] = (__bf16)(v0.x * sc); o[1] = (__bf16)(v0.y * sc);
    o[2] = (__bf16)(v0.z * sc); o[3] = (__bf16)(v0.w * sc);
    o[4] = (__bf16)(v1.x * sc); o[5] = (__bf16)(v1.y * sc);
    o[6] = (__bf16)(v1.z * sc); o[7] = (__bf16)(v1.w * sc);
    *(bf16x8*)(out + (size_t)row * CDIM + lane * 8) = o;
}

// ---------- kernel 3: fused bf16 MFMA sim + per-chunk top-5 -----------------
// grid = (NC, BS/TQ), block = 256 (4 waves). Wave owns 32 queries (A persistent
// in 128 VGPRs), computes 32q x 32n per tile, K=512 inner.
__global__ __launch_bounds__(256, 2) void simtopk(
        const ushort_t* __restrict__ qn, const ushort_t* __restrict__ mn,
        unsigned* __restrict__ cand) {
    __shared__ __align__(16) ushort_t Bt[TN][CDIM + 8];   // +8 bf16 pad per row

    const int tid  = threadIdx.x;
    const int wave = tid >> 6, lane = tid & 63;
    const int quad = lane >> 4, c16 = lane & 15;
    const int nc = blockIdx.x;                 // 0..7  (fast-varying -> XCD-local B chunk)
    const int qt = blockIdx.y;                 // 0..63
    const int qw = qt * TQ + wave * 32;
    const int nb0 = nc * CHUNK;

    // persistent A fragments: 2 q-subtiles x 16 K-chunks
    bf16x8 a0[16], a1[16];
    {
        const ushort_t* p0 = qn + (size_t)(qw + c16) * CDIM + quad * 8;
#pragma unroll
        for (int kc = 0; kc < 16; ++kc) {
            a0[kc] = *(const bf16x8*)(p0 + kc * 32);
            a1[kc] = *(const bf16x8*)(p0 + 16 * CDIM + kc * 32);
        }
    }

    unsigned keys[8][KTOP];
#pragma unroll
    for (int l = 0; l < 8; ++l)
#pragma unroll
        for (int j = 0; j < KTOP; ++j) keys[l][j] = 0u;

    const int stage_r = tid >> 3;              // 0..31
    const int stage_c = (tid & 7) * 8;         // 0..56

    for (int it = 0; it < CHUNK / TN; ++it) {
        const int nb = nb0 + it * TN;
        // stage B tile: 32 rows x 1KB, 128B per thread, coalesced 128B segments
        {
            const ushort_t* src = mn + (size_t)(nb + stage_r) * CDIM + stage_c;
#pragma unroll
            for (int j = 0; j < 8; ++j)
                *(bf16x8*)&Bt[stage_r][stage_c + j * 64] = *(const bf16x8*)(src + j * 64);
        }
        __syncthreads();

        f32x4 acc00 = {0.f, 0.f, 0.f, 0.f}, acc01 = {0.f, 0.f, 0.f, 0.f};
        f32x4 acc10 = {0.f, 0.f, 0.f, 0.f}, acc11 = {0.f, 0.f, 0.f, 0.f};
#pragma unroll
        for (int kc = 0; kc < 16; ++kc) {
            bf16x8 b0 = *(const bf16x8*)&Bt[c16][kc * 32 + quad * 8];
            bf16x8 b1 = *(const bf16x8*)&Bt[16 + c16][kc * 32 + quad * 8];
            acc00 = __builtin_amdgcn_mfma_f32_16x16x32_bf16(a0[kc], b0, acc00, 0, 0, 0);
            acc01 = __builtin_amdgcn_mfma_f32_16x16x32_bf16(a0[kc], b1, acc01, 0, 0, 0);
            acc10 = __builtin_amdgcn_mfma_f32_16x16x32_bf16(a1[kc], b0, acc10, 0, 0, 0);
            acc11 = __builtin_amdgcn_mfma_f32_16x16x32_bf16(a1[kc], b1, acc11, 0, 0, 0);
        }
        __syncthreads();

        const int n0 = nb + c16, n1 = nb + 16 + c16;
        upd4<0>(acc00, keys, n0);
        upd4<0>(acc01, keys, n1);
        upd4<4>(acc10, keys, n0);
        upd4<4>(acc11, keys, n1);
    }

    // merge the 16 column-lanes of each quad (disjoint n subsets -> union top5)
#pragma unroll
    for (int d = 1; d <= 8; d <<= 1) {
#pragma unroll
        for (int l = 0; l < 8; ++l) {
            unsigned rk[KTOP];
#pragma unroll
            for (int j = 0; j < KTOP; ++j) rk[j] = (unsigned)__shfl_xor((int)keys[l][j], d);
#pragma unroll
            for (int j = 0; j < KTOP; ++j) ins_nb(keys[l], rk[j]);
        }
    }

    // writer lane c16==l emits list l for query qw + qs*16 + quad*4 + r
#pragma unroll
    for (int l = 0; l < 8; ++l) {
        if (c16 == l) {
            const int qs = l >> 2, r = l & 3;
            const int q = qw + qs * 16 + quad * 4 + r;
            unsigned* cp = cand + ((size_t)q * NC + nc) * KTOP;
#pragma unroll
            for (int j = 0; j < KTOP; ++j) cp[j] = keys[l][j];
        }
    }
}

// ---------- kernel 4: global top-5 merge + softmax + gather + residual ------
__global__ void epilogue(const float* __restrict__ x, const float* __restrict__ mem,
                         const unsigned* __restrict__ cand, float* __restrict__ out) {
    int wave = threadIdx.x >> 6, lane = threadIdx.x & 63;
    int q = blockIdx.x * 4 + wave;

    unsigned key = (lane < NC * KTOP) ? cand[(size_t)q * (NC * KTOP) + lane] : 0u;
    float s[KTOP]; int id[KTOP];
#pragma unroll
    for (int k = 0; k < KTOP; ++k) {
        unsigned m = key;
#pragma unroll
        for (int d = 32; d; d >>= 1) {
            unsigned o = (unsigned)__shfl_xor((int)m, d);
            m = o > m ? o : m;
        }
        s[k] = dec_score(m);
        id[k] = (int)(m & 0x7FFFu);
        unsigned long long b = __ballot(key == m);
        int first = __ffsll((long long)b) - 1;
        if (lane == first) key = 0u;
    }
    float w[KTOP], sum = 0.f;
#pragma unroll
    for (int k = 0; k < KTOP; ++k) { w[k] = expf(s[k] - s[0]); sum += w[k]; }
    float inv = 0.5f / sum;

    int c = lane * 8;
    const float4* xp = (const float4*)(x + (size_t)q * CDIM + c);
    float4 o0 = xp[0], o1 = xp[1];
#pragma unroll
    for (int k = 0; k < KTOP; ++k) {
        float wk = w[k] * inv;
        const float4* mp = (const float4*)(mem + (size_t)id[k] * CDIM + c);
        float4 g0 = mp[0], g1 = mp[1];
        o0.x += wk * g0.x; o0.y += wk * g0.y; o0.z += wk * g0.z; o0.w += wk * g0.w;
        o1.x += wk * g1.x; o1.y += wk * g1.y; o1.z += wk * g1.z; o1.w += wk * g1.w;
    }
    float* op = out + (size_t)q * CDIM + c;
    *(float4*)op = o0;
    *(float4*)(op + 4) = o1;
}

// ---------- launcher --------------------------------------------------------
extern "C" void kernel_launch(void* const* d_in, const int* in_sizes, int n_in,
                              void* d_out, int out_size, void* d_ws, size_t ws_size,
                              hipStream_t stream) {
    const float* x    = (const float*)d_in[0];   // [4,2048,512] fp32
    const float* memM = (const float*)d_in[1];   // [32768,512] fp32
    float* out = (float*)d_out;                  // fp32 output

    // workspace layout: mn bf16 [M][C] | qn bf16 [BS][C] | cand u32 [BS][NC][5]
    ushort_t* mn = (ushort_t*)d_ws;
    ushort_t* qn = mn + (size_t)MROWS * CDIM;
    unsigned* cand = (unsigned*)(qn + (size_t)BS * CDIM);

    nrm_cast<<<MROWS / 4, 256, 0, stream>>>(memM, mn, MROWS);
    nrm_cast<<<BS / 4, 256, 0, stream>>>(x, qn, BS);
    simtopk<<<dim3(NC, BS / TQ), 256, 0, stream>>>(qn, mn, cand);
    epilogue<<<BS / 4, 256, 0, stream>>>(x, memM, cand, out);
}